// Round 11
// baseline (818.643 us; speedup 1.0000x reference)
//
#include <hip/hip_runtime.h>

#define B_ 64
#define L_ 2048
#define G_ 512
#define F_ 3072
#define N_ 5632
#define NT_ 360448
#define EG_ 16384
#define E_ 1048576
#define EPS_ 1e-5f
#define CST_ 66      // cat tile stride in ushorts (33 dwords, odd -> ~2-way banks)
#define KTOT_ 3584   // md GEMM K = G + F
#define KCH_ 896     // md GEMM K-chunk (4 chunks)
#define KP_ 384      // per-tile source-list capacity (measured span ~230 max)
#define SST_ 72      // ST stride in ushorts (144 B: 16B-aligned rows for b128 reads)

typedef __attribute__((ext_vector_type(8))) short bf8v;
typedef __attribute__((ext_vector_type(4))) float f4v;

__device__ __forceinline__ unsigned short f2bf(float f){
  unsigned int u=__float_as_uint(f);
  unsigned int r=(u + 0x7fffu + ((u>>16)&1u))>>16;
  return (unsigned short)r;
}
__device__ __forceinline__ float bf2f(unsigned short h){
  return __uint_as_float(((unsigned int)h)<<16);
}

// ---------------- fused init: cnt=0, mdT=0, wcat build ----------------
__global__ void k_init(int* __restrict__ cnt, float* __restrict__ mdT,
                       const float* __restrict__ wrel, const float* __restrict__ wroot,
                       unsigned short* __restrict__ wcat){
  int i=blockIdx.x*256+threadIdx.x;      // grid covers L_*64 = 131072
  if(i<L_*64) mdT[i]=0.f;
  if(i<N_) cnt[i]=0;
  if(i<32768){
    int l=i>>13; int rest=i&8191; int n=rest>>7; int k=rest&127;
    float v=(k<64)? wrel[((long)l*64+n)*64+k] : wroot[((long)l*64+n)*64+(k-64)];
    wcat[i]=f2bf(v);
  }
}

// ---------------- CSR build (shared topology = first EG edges, graph 0) ----------------
__global__ void k_hist(const int* __restrict__ ei, int* __restrict__ cnt){
  int e=blockIdx.x*256+threadIdx.x;
  if(e<EG_) atomicAdd(&cnt[ei[E_+e]],1);
}

// shuffle-based scan
__global__ void k_scan(const int* __restrict__ cnt, int* __restrict__ off, int* __restrict__ cur){
  __shared__ int wsum[16];
  __shared__ int carry_s;
  int t=threadIdx.x, lane=t&63, wid=t>>6;
  if(t==0) carry_s=0;
  __syncthreads();
  for(int base=0;base<N_;base+=1024){
    int i=base+t;
    int v=(i<N_)?cnt[i]:0;
    int s=v;
    #pragma unroll
    for(int o=1;o<64;o<<=1){ int u=__shfl_up(s,o,64); if(lane>=o) s+=u; }
    if(lane==63) wsum[wid]=s;
    __syncthreads();
    if(t==0){
      int run=carry_s;
      #pragma unroll
      for(int q=0;q<16;q++){ int tmp=wsum[q]; wsum[q]=run; run+=tmp; }
      carry_s=run;
    }
    __syncthreads();
    int ex=wsum[wid]+s-v;
    if(i<N_){ off[i]=ex; cur[i]=ex; }
    __syncthreads();
  }
  if(t==0) off[N_]=carry_s;
}

// pack src|dst<<16 per edge (both < 5632 < 2^16)
__global__ void k_scatter(const int* __restrict__ ei, int* __restrict__ cur, int* __restrict__ srcs){
  int e=blockIdx.x*256+threadIdx.x;
  if(e<EG_){
    int d=ei[E_+e];
    int p=atomicAdd(&cur[d],1);
    srcs[p]=ei[e] | (d<<16);
  }
}

// ---------------- per-tile dense aggregation operator: M_j [64][KP_], source list S_j ----------------
// one block per 64-dst tile; dedup sources, build M (bf16 counts: exact small ints)
__global__ void k_prep(const int* __restrict__ off, const int* __restrict__ srcs,
                       unsigned short* __restrict__ M, int* __restrict__ slist, int* __restrict__ scnt){
  __shared__ unsigned short map[N_];
  __shared__ unsigned short Ml[64*KP_];
  int j=blockIdx.x, tid=threadIdx.x;
  int nb=j*64;
  for(int i=tid;i<N_;i+=256) map[i]=0xffff;
  for(int i=tid;i<64*KP_;i+=256) Ml[i]=0;
  __syncthreads();
  if(tid==0){
    int e0=off[nb], e1=off[nb+64];
    int c=0;
    for(int e=e0;e<e1;e++){
      int u=srcs[e];
      int s=u&0xffff, d=(u>>16)-nb;
      int slot=map[s];
      if(slot==0xffff){
        if(c<KP_){ slot=c; map[s]=(unsigned short)c; slist[j*KP_+c]=s; c++; }
        else slot=KP_-1;   // overflow guard (not expected: span max ~230 << 384)
      }
      float curv=bf2f(Ml[d*KP_+slot]);
      Ml[d*KP_+slot]=f2bf(curv+1.f);
    }
    scnt[j]=c;
  }
  __syncthreads();
  for(int i=tid;i<64*KP_;i+=256) M[(size_t)j*64*KP_+i]=Ml[i];
}

// ---------------- encoder + fused LN (produces hnA bf16 for layer 0) ----------------
__global__ __launch_bounds__(256) void k_enc(const float* __restrict__ x, unsigned short* __restrict__ hn,
    const float* __restrict__ ew, const float* __restrict__ eb,
    const float* __restrict__ lng, const float* __restrict__ lnb){
  int lane=threadIdx.x&63, wid=threadIdx.x>>6;
  int node0=blockIdx.x*32+wid*8;
  float w[7];
  #pragma unroll
  for(int k=0;k<7;k++) w[k]=ew[lane*7+k];
  float bias=eb[lane], gam=lng[lane], bet=lnb[lane];
  for(int t=0;t<8;t++){
    long n=node0+t;
    float acc=bias;
    #pragma unroll
    for(int k=0;k<7;k++) acc += x[n*7+k]*w[k];
    acc=fmaxf(acc,0.f);
    float s1=acc, s2=acc*acc;
    #pragma unroll
    for(int o=32;o>0;o>>=1){ s1+=__shfl_xor(s1,o,64); s2+=__shfl_xor(s2,o,64); }
    float mu=s1*(1.f/64.f);
    float var=s2*(1.f/64.f)-mu*mu;
    float inv=rsqrtf(var+EPS_);
    hn[n*64+lane]=f2bf((acc-mu)*inv*gam+bet);
  }
}

// ---------------- fused layer: staged-MFMA aggregation -> MFMA transform -> epilogue ----------------
// agg_tile = M_j · hn[S_j] via chunked MFMA (64 slots/chunk, dependence-free staging),
// then [agg|root] @ Wcat^T with fused bias/relu/LN.
__global__ __launch_bounds__(256,6) void k_layer(const unsigned short* __restrict__ hs,
    unsigned short* __restrict__ hd, const unsigned short* __restrict__ M,
    const int* __restrict__ slist, const int* __restrict__ scnt,
    const unsigned short* __restrict__ wcat, const float* __restrict__ brel,
    const float* __restrict__ lng, const float* __restrict__ lnb, int do_ln){
  __shared__ unsigned short ST[64*SST_];   // [chan][slot_local]
  __shared__ unsigned short cat[64*CST_];  // agg rows for phase-2 A-frags
  int tid=threadIdx.x;
  int w=tid>>6, lane=tid&63;
  int bid=blockIdx.x;
  const int P=N_/64;                 // 88 tiles per graph
  int r8=bid/(8*P), rem=bid%(8*P);
  int xcd=rem&7, jj=rem>>3, g=r8*8+xcd;   // one graph per XCD's L2
  int nodebase=jj*64;
  const unsigned short* hg = hs + (size_t)g*N_*64;
  int m=lane&15, quad=lane>>4;
  int w16=w*16;

  int cnt=__builtin_amdgcn_readfirstlane(scnt[jj]);
  const int* sl=slist + (size_t)jj*KP_;
  const unsigned short* Mj=M + (size_t)jj*64*KP_;

  // ---- phase 1: chunked MFMA aggregation ----
  f4v acc1[4];
  #pragma unroll
  for(int nt=0;nt<4;nt++) acc1[nt]=(f4v){0.f,0.f,0.f,0.f};
  int nch=(cnt+63)>>6;
  for(int ch=0;ch<nch;ch++){
    int base=ch*64;
    // stage: wave w loads 16 source rows (independent, coalesced 128 B each)
    #pragma unroll 4
    for(int t=0;t<16;t++){
      int slot=base+w16+t;
      unsigned short v=0;
      if(slot<cnt){
        int s=__builtin_amdgcn_readfirstlane(sl[slot]);
        v=hg[(size_t)s*64+lane];
      }
      ST[lane*SST_ + w16+t]=v;
    }
    __syncthreads();
    const unsigned short* arow=Mj + (size_t)(w16+m)*KP_ + base;
    bf8v a0=*(const bf8v*)(arow + quad*8);
    bf8v a1=*(const bf8v*)(arow + 32 + quad*8);
    #pragma unroll
    for(int nt=0;nt<4;nt++){
      int c=nt*16+m;
      bf8v b0=*(const bf8v*)&ST[c*SST_ + quad*8];
      bf8v b1=*(const bf8v*)&ST[c*SST_ + 32 + quad*8];
      acc1[nt]=__builtin_amdgcn_mfma_f32_16x16x32_bf16(a0,b0,acc1[nt],0,0,0);
      acc1[nt]=__builtin_amdgcn_mfma_f32_16x16x32_bf16(a1,b1,acc1[nt],0,0,0);
    }
    __syncthreads();
  }
  // write agg to cat (C layout: row=w16+quad*4+r, col=nt*16+m)
  #pragma unroll
  for(int r=0;r<4;r++)
    #pragma unroll
    for(int nt=0;nt<4;nt++)
      cat[(w16+quad*4+r)*CST_ + nt*16+m]=f2bf(acc1[nt][r]);
  __syncthreads();

  // ---- phase 2: MFMA [agg|root] @ Wcat^T, fused epilogue ----
  int row=w16+m;
  const unsigned short* arow=&cat[row*CST_];
  bf8v af0=*(const bf8v*)(arow + quad*8);
  bf8v af1=*(const bf8v*)(arow + 32 + quad*8);
  const unsigned short* hrow=hg+(size_t)(nodebase+row)*64;
  bf8v af2=*(const bf8v*)(hrow+quad*8);
  bf8v af3=*(const bf8v*)(hrow+32+quad*8);
  f4v acc[4];
  float bias_nt[4], g_nt[4], b_nt[4];
  #pragma unroll
  for(int nt=0;nt<4;nt++){
    int c=nt*16+m;
    bias_nt[nt]=brel[c];
    g_nt[nt]=lng[c]; b_nt[nt]=lnb[c];
    acc[nt]=(f4v){0.f,0.f,0.f,0.f};
    const unsigned short* wrow=wcat + (long)c*128 + quad*8;
    bf8v b0=*(const bf8v*)(wrow);
    bf8v b1=*(const bf8v*)(wrow+32);
    bf8v b2=*(const bf8v*)(wrow+64);
    bf8v b3=*(const bf8v*)(wrow+96);
    acc[nt]=__builtin_amdgcn_mfma_f32_16x16x32_bf16(af0,b0,acc[nt],0,0,0);
    acc[nt]=__builtin_amdgcn_mfma_f32_16x16x32_bf16(af1,b1,acc[nt],0,0,0);
    acc[nt]=__builtin_amdgcn_mfma_f32_16x16x32_bf16(af2,b2,acc[nt],0,0,0);
    acc[nt]=__builtin_amdgcn_mfma_f32_16x16x32_bf16(af3,b3,acc[nt],0,0,0);
  }
  float v[4][4];
  #pragma unroll
  for(int nt=0;nt<4;nt++)
    #pragma unroll
    for(int r=0;r<4;r++)
      v[nt][r]=fmaxf(acc[nt][r]+bias_nt[nt],0.f);
  if(do_ln){
    #pragma unroll
    for(int r=0;r<4;r++){
      float rs=v[0][r]+v[1][r]+v[2][r]+v[3][r];
      float rss=v[0][r]*v[0][r]+v[1][r]*v[1][r]+v[2][r]*v[2][r]+v[3][r]*v[3][r];
      #pragma unroll
      for(int o=1;o<16;o<<=1){ rs+=__shfl_xor(rs,o,64); rss+=__shfl_xor(rss,o,64); }
      float mu=rs*(1.f/64.f);
      float var=rss*(1.f/64.f)-mu*mu;
      float inv=rsqrtf(var+EPS_);
      #pragma unroll
      for(int nt=0;nt<4;nt++) v[nt][r]=(v[nt][r]-mu)*inv*g_nt[nt]+b_nt[nt];
    }
  }
  size_t rowbase=(size_t)g*N_ + nodebase + w16 + quad*4;
  #pragma unroll
  for(int r=0;r<4;r++){
    unsigned short* out=hd + (rowbase+r)*64;
    #pragma unroll
    for(int nt=0;nt<4;nt++) out[nt*16+m]=f2bf(v[nt][r]);
  }
}

// ---------------- merged readouts; also emit double-bf16 pf rows for md GEMM ----------------
__global__ __launch_bounds__(256) void k_readout2(const unsigned short* __restrict__ h,
    const int* __restrict__ prodi, const int* __restrict__ linei,
    const float* __restrict__ pw, const float* __restrict__ pb,
    const float* __restrict__ fw, const float* __restrict__ fb,
    float* __restrict__ outp, float* __restrict__ outf,
    unsigned short* __restrict__ pfhi, unsigned short* __restrict__ pflo){
  int i=blockIdx.x*256+threadIdx.x;
  const int MP=B_*G_;
  const int MT=MP+B_*F_;
  if(i>=MT) return;
  bool isp=i<MP;
  int j=isp? i : i-MP;
  long n=isp? (long)prodi[j] : (long)linei[j];
  const float* wv=isp? pw:fw;
  float acc=isp? pb[0]:fb[0];
  const uint4* hp=(const uint4*)(h+n*64);
  #pragma unroll
  for(int c=0;c<8;c++){
    uint4 u=hp[c];
    unsigned int uu[4]={u.x,u.y,u.z,u.w};
    #pragma unroll
    for(int q=0;q<4;q++){
      float lo=__uint_as_float(uu[q]<<16);
      float hi=__uint_as_float(uu[q]&0xffff0000u);
      acc += lo*wv[c*8+2*q] + hi*wv[c*8+2*q+1];
    }
  }
  int b,kcol;
  if(isp){ outp[j]=acc; b=j/G_; kcol=j%G_; }
  else   { outf[j]=acc; b=j/F_; kcol=G_+j%F_; }
  unsigned short hi=f2bf(acc);
  pfhi[(long)b*KTOT_+kcol]=hi;
  pflo[(long)b*KTOT_+kcol]=f2bf(acc-bf2f(hi));
}

// ---------------- md dense GEMM: mdT[l][b] += sum_k mask[l][k]*pf[b][k] ----------------
__global__ __launch_bounds__(256) void k_md_gemm(const float* __restrict__ gm, const float* __restrict__ lm,
    const unsigned short* __restrict__ pfhi, const unsigned short* __restrict__ pflo,
    float* __restrict__ mdT){
  int tid=threadIdx.x;
  int w=tid>>6, lane=tid&63;
  int m=lane&15, quad=lane>>4;
  int lb=blockIdx.x>>2, kc=blockIdx.x&3;
  int l=lb*64 + w*16 + m;              // A (mask) row for this lane
  f4v acc[4];
  #pragma unroll
  for(int nt=0;nt<4;nt++) acc[nt]=(f4v){0.f,0.f,0.f,0.f};
  int kk0=kc*KCH_;
  for(int s=0;s<KCH_/32;s++){
    int kk=kk0+s*32;
    const float* ap = (kk<G_)? gm + (long)l*G_ + kk : lm + (long)l*F_ + (kk-G_);
    float4 a0=*(const float4*)(ap+quad*8);
    float4 a1=*(const float4*)(ap+quad*8+4);
    bf8v af;
    af[0]=(short)f2bf(a0.x); af[1]=(short)f2bf(a0.y);
    af[2]=(short)f2bf(a0.z); af[3]=(short)f2bf(a0.w);
    af[4]=(short)f2bf(a1.x); af[5]=(short)f2bf(a1.y);
    af[6]=(short)f2bf(a1.z); af[7]=(short)f2bf(a1.w);
    #pragma unroll
    for(int nt=0;nt<4;nt++){
      int b=nt*16+m;
      const unsigned short* bp=pfhi + (long)b*KTOT_ + kk + quad*8;
      const unsigned short* lp=pflo + (long)b*KTOT_ + kk + quad*8;
      bf8v bh=*(const bf8v*)bp;
      bf8v bl=*(const bf8v*)lp;
      acc[nt]=__builtin_amdgcn_mfma_f32_16x16x32_bf16(af,bh,acc[nt],0,0,0);
      acc[nt]=__builtin_amdgcn_mfma_f32_16x16x32_bf16(af,bl,acc[nt],0,0,0);
    }
  }
  int lrow=lb*64 + w*16 + quad*4;
  #pragma unroll
  for(int r=0;r<4;r++)
    #pragma unroll
    for(int nt=0;nt<4;nt++)
      atomicAdd(&mdT[(long)(lrow+r)*64 + nt*16 + m], acc[nt][r]);
}

__global__ void k_md_final(const float* __restrict__ x, const int* __restrict__ loc,
    const float* __restrict__ mdT, float* __restrict__ md){
  int i=blockIdx.x*256+threadIdx.x;   // i = b*L + l
  if(i<B_*L_){
    int b=i/L_, l=i%L_;
    md[i]=x[(long)loc[i]*7]-mdT[(long)l*64+b];
  }
}

extern "C" void kernel_launch(void* const* d_in, const int* in_sizes, int n_in,
                              void* d_out, int out_size, void* d_ws, size_t ws_size,
                              hipStream_t stream){
  const float* x    =(const float*)d_in[0];
  const int*   ei   =(const int*)d_in[1];
  const int*   prodi=(const int*)d_in[2];
  const int*   linei=(const int*)d_in[3];
  const int*   loci =(const int*)d_in[4];
  const float* ew   =(const float*)d_in[5];
  const float* eb   =(const float*)d_in[6];
  const float* lng  =(const float*)d_in[7];
  const float* lnb  =(const float*)d_in[8];
  const float* wrel =(const float*)d_in[9];
  const float* brel =(const float*)d_in[10];
  const float* wroot=(const float*)d_in[11];
  const float* pw   =(const float*)d_in[12];
  const float* pb   =(const float*)d_in[13];
  const float* fw   =(const float*)d_in[14];
  const float* fb   =(const float*)d_in[15];
  const float* gm   =(const float*)d_in[16];
  const float* lm   =(const float*)d_in[17];

  char* ws=(char*)d_ws;
  unsigned short* hnA =(unsigned short*)ws;                        // NT*64 bf16
  unsigned short* hnB =hnA + (size_t)NT_*64;                       // NT*64 bf16
  unsigned short* wcat=hnB + (size_t)NT_*64;                       // 32768 bf16
  unsigned short* pfhi=wcat + 32768;                               // B*KTOT bf16
  unsigned short* pflo=pfhi + (size_t)B_*KTOT_;                    // B*KTOT bf16
  unsigned short* M   =pflo + (size_t)B_*KTOT_;                    // 88*64*KP bf16 (4.3 MB)
  float* mdT=(float*)(M + (size_t)88*64*KP_);                      // L*64 f32
  int* cnt =(int*)(mdT + (size_t)L_*64);
  int* off = cnt + N_;
  int* cur = off + (N_+1);
  int* srcs= cur + N_;
  int* slist=srcs + EG_;                                           // 88*KP int
  int* scnt =slist + 88*KP_;                                       // 88 int

  float* outp =(float*)d_out;
  float* outf =outp + (size_t)B_*G_;
  float* outmd=outf + (size_t)B_*F_;

  k_init<<<512,256,0,stream>>>(cnt,mdT,wrel,wroot,wcat);
  k_hist<<<64,256,0,stream>>>(ei,cnt);
  k_scan<<<1,1024,0,stream>>>(cnt,off,cur);
  k_scatter<<<64,256,0,stream>>>(ei,cur,srcs);
  k_prep<<<88,256,0,stream>>>(off,srcs,M,slist,scnt);
  k_enc<<<NT_/32,256,0,stream>>>(x,hnA,ew,eb,lng,lnb);
  for(int i=0;i<4;i++){
    const unsigned short* hs=(i&1)?hnB:hnA;
    unsigned short* hd=(i&1)?hnA:hnB;
    k_layer<<<B_*(N_/64),256,0,stream>>>(hs,hd,M,slist,scnt,wcat+(size_t)i*8192,
        brel+(size_t)i*64,lng,lnb,(i<3)?1:0);
  }
  // after 4 layers (A->B->A->B->A) result is in hnA
  {
    int MT=B_*(G_+F_);
    k_readout2<<<(MT+255)/256,256,0,stream>>>(hnA,prodi,linei,pw,pb,fw,fb,outp,outf,pfhi,pflo);
  }
  k_md_gemm<<<128,256,0,stream>>>(gm,lm,pfhi,pflo,mdT);
  k_md_final<<<(B_*L_)/256,256,0,stream>>>(x,loci,mdT,outmd);
}

// Round 12
// 522.715 us; speedup vs baseline: 1.5661x; 1.5661x over previous
//
#include <hip/hip_runtime.h>

#define B_ 64
#define L_ 2048
#define G_ 512
#define F_ 3072
#define N_ 5632
#define NT_ 360448
#define EG_ 16384
#define E_ 1048576
#define EPS_ 1e-5f
#define CST_ 66      // cat tile stride in ushorts (33 dwords, odd -> ~2-way banks)
#define KTOT_ 3584   // md GEMM K = G + F
#define KCH_ 896     // md GEMM K-chunk (4 chunks)
#define TCAP_ 384    // per-tile edge capacity (realized max span ~255)

typedef __attribute__((ext_vector_type(8))) short bf8v;
typedef __attribute__((ext_vector_type(4))) float f4v;

__device__ __forceinline__ unsigned short f2bf(float f){
  unsigned int u=__float_as_uint(f);
  unsigned int r=(u + 0x7fffu + ((u>>16)&1u))>>16;
  return (unsigned short)r;
}
__device__ __forceinline__ float bf2f(unsigned short h){
  return __uint_as_float(((unsigned int)h)<<16);
}

// ---------------- single prep dispatch ----------------
// blocks 0..87: per-tile CSR build (LDS hist -> scan -> scatter), packed (src|dst<<16)
// blocks 88..599: mdT zero + wcat build
__global__ __launch_bounds__(256) void k_prep(const int* __restrict__ ei,
    float* __restrict__ mdT, unsigned short* __restrict__ wcat,
    const float* __restrict__ wrel, const float* __restrict__ wroot,
    int* __restrict__ offT, int* __restrict__ srcs2){
  int bid=blockIdx.x, tid=threadIdx.x;
  if(bid>=88){
    int i=(bid-88)*256+tid;          // 512 blocks -> 131072
    if(i<L_*64) mdT[i]=0.f;
    if(i<32768){
      int l=i>>13; int rest=i&8191; int n=rest>>7; int k=rest&127;
      float v=(k<64)? wrel[((long)l*64+n)*64+k] : wroot[((long)l*64+n)*64+(k-64)];
      wcat[i]=f2bf(v);
    }
    return;
  }
  __shared__ int cnt64[64], cur64[64];
  int nb=bid*64;
  if(tid<64) cnt64[tid]=0;
  __syncthreads();
  for(int e=tid;e<EG_;e+=256){
    int d=ei[E_+e];
    unsigned t=(unsigned)(d-nb);
    if(t<64u) atomicAdd(&cnt64[t],1);
  }
  __syncthreads();
  if(tid<64){
    int v=cnt64[tid], s=v;
    #pragma unroll
    for(int o=1;o<64;o<<=1){ int u=__shfl_up(s,o,64); if(tid>=o) s+=u; }
    int ex=s-v;
    offT[bid*65+tid]=ex;
    cur64[tid]=ex;
    if(tid==63) offT[bid*65+64]=s;
  }
  __syncthreads();
  for(int e=tid;e<EG_;e+=256){
    int s=ei[e];
    int d=ei[E_+e];
    unsigned t=(unsigned)(d-nb);
    if(t<64u){
      int p=atomicAdd(&cur64[t],1);
      if(p<TCAP_) srcs2[bid*TCAP_+p]=s|(d<<16);
    }
  }
}

// ---------------- encoder + fused LN (produces hnA bf16 for layer 0) ----------------
__global__ __launch_bounds__(256) void k_enc(const float* __restrict__ x, unsigned short* __restrict__ hn,
    const float* __restrict__ ew, const float* __restrict__ eb,
    const float* __restrict__ lng, const float* __restrict__ lnb){
  int lane=threadIdx.x&63, wid=threadIdx.x>>6;
  int node0=blockIdx.x*32+wid*8;
  float w[7];
  #pragma unroll
  for(int k=0;k<7;k++) w[k]=ew[lane*7+k];
  float bias=eb[lane], gam=lng[lane], bet=lnb[lane];
  for(int t=0;t<8;t++){
    long n=node0+t;
    float acc=bias;
    #pragma unroll
    for(int k=0;k<7;k++) acc += x[n*7+k]*w[k];
    acc=fmaxf(acc,0.f);
    float s1=acc, s2=acc*acc;
    #pragma unroll
    for(int o=32;o>0;o>>=1){ s1+=__shfl_xor(s1,o,64); s2+=__shfl_xor(s2,o,64); }
    float mu=s1*(1.f/64.f);
    float var=s2*(1.f/64.f)-mu*mu;
    float inv=rsqrtf(var+EPS_);
    hn[n*64+lane]=f2bf((acc-mu)*inv*gam+bet);
  }
}

// ---------------- fused layer: pipelined gather -> MFMA -> epilogue (barrier-free) ----------------
// wave w owns dst rows [w*16,w*16+16); lane = channel. 3-stage pipeline:
// consume rows(g) while rows(g+1) are in flight and edge-words(g+2) are being fetched.
__global__ __launch_bounds__(256,6) void k_layer(const unsigned short* __restrict__ hs,
    unsigned short* __restrict__ hd, const int* __restrict__ offT, const int* __restrict__ srcs2,
    const unsigned short* __restrict__ wcat, const float* __restrict__ brel,
    const float* __restrict__ lng, const float* __restrict__ lnb, int do_ln){
  __shared__ unsigned short cat[64*CST_];
  int tid=threadIdx.x;
  int w=tid>>6, lane=tid&63;
  int bid=blockIdx.x;
  const int P=N_/64;                 // 88 tiles per graph
  int r8=bid/(8*P), rem=bid%(8*P);
  int xcd=rem&7, jj=rem>>3, g=r8*8+xcd;   // one graph per XCD's L2
  int nodebase=jj*64;
  const unsigned short* hg = hs + (size_t)g*N_*64;
  int w16=w*16;

  // ---- phase 1: software-pipelined gather with sorted-dst running flush ----
  {
    int kb=__builtin_amdgcn_readfirstlane(offT[jj*65+w16]);
    int ke=__builtin_amdgcn_readfirstlane(offT[jj*65+w16+16]);
    const int* esp=srcs2 + jj*TCAP_;
    float acc=0.f;
    int dcur=w16;
#define FLUSH_(dd) while(dcur<(dd)){ cat[dcur*CST_+lane]=f2bf(acc); acc=0.f; dcur++; }
    int ng=(ke-kb)>>2;
    int u0=0,u1=0,u2=0,u3=0, v0=0,v1=0,v2=0,v3=0;
    unsigned short a0=0,a1=0,a2=0,a3=0;
    if(ng>0){
      u0=esp[kb];u1=esp[kb+1];u2=esp[kb+2];u3=esp[kb+3];
      a0=hg[(size_t)(u0&0xffff)*64+lane];
      a1=hg[(size_t)(u1&0xffff)*64+lane];
      a2=hg[(size_t)(u2&0xffff)*64+lane];
      a3=hg[(size_t)(u3&0xffff)*64+lane];
    }
    if(ng>1){
      v0=esp[kb+4];v1=esp[kb+5];v2=esp[kb+6];v3=esp[kb+7];
    }
    for(int gi=0;gi<ng;gi++){
      unsigned short b0=0,b1=0,b2=0,b3=0;
      if(gi+1<ng){                    // issue rows for next group (words already resident)
        b0=hg[(size_t)(v0&0xffff)*64+lane];
        b1=hg[(size_t)(v1&0xffff)*64+lane];
        b2=hg[(size_t)(v2&0xffff)*64+lane];
        b3=hg[(size_t)(v3&0xffff)*64+lane];
      }
      int w0=0,w1=0,w2=0,w3=0;
      if(gi+2<ng){                    // fetch edge words two groups ahead
        int kn=kb+(gi+2)*4;
        w0=esp[kn];w1=esp[kn+1];w2=esp[kn+2];w3=esp[kn+3];
      }
      // consume current group's rows
      int d0=(u0>>16)-nodebase; FLUSH_(d0); acc+=bf2f(a0);
      int d1=(u1>>16)-nodebase; FLUSH_(d1); acc+=bf2f(a1);
      int d2=(u2>>16)-nodebase; FLUSH_(d2); acc+=bf2f(a2);
      int d3=(u3>>16)-nodebase; FLUSH_(d3); acc+=bf2f(a3);
      u0=v0;u1=v1;u2=v2;u3=v3;
      v0=w0;v1=w1;v2=w2;v3=w3;
      a0=b0;a1=b1;a2=b2;a3=b3;
    }
    for(int k=kb+ng*4;k<ke;k++){      // tail
      int u=__builtin_amdgcn_readfirstlane(esp[k]);
      unsigned short a=hg[(size_t)(u&0xffff)*64+lane];
      int d=(u>>16)-nodebase; FLUSH_(d); acc+=bf2f(a);
    }
    FLUSH_(w16+16);
#undef FLUSH_
  }
  // no barrier: wave w writes and reads only cat rows [w16, w16+16)

  // ---- phase 2: MFMA [agg|root] @ Wcat^T, fused epilogue ----
  int m=lane&15, quad=lane>>4;
  int row=w16+m;
  const unsigned short* arow=&cat[row*CST_];
  bf8v af0=*(const bf8v*)(arow + quad*8);
  bf8v af1=*(const bf8v*)(arow + 32 + quad*8);
  const unsigned short* hrow=hg+(size_t)(nodebase+row)*64;
  bf8v af2=*(const bf8v*)(hrow+quad*8);
  bf8v af3=*(const bf8v*)(hrow+32+quad*8);
  f4v acc[4];
  float bias_nt[4], g_nt[4], b_nt[4];
  #pragma unroll
  for(int nt=0;nt<4;nt++){
    int c=nt*16+m;
    bias_nt[nt]=brel[c];
    g_nt[nt]=lng[c]; b_nt[nt]=lnb[c];
    acc[nt]=(f4v){0.f,0.f,0.f,0.f};
    const unsigned short* wrow=wcat + (long)c*128 + quad*8;
    bf8v b0=*(const bf8v*)(wrow);
    bf8v b1=*(const bf8v*)(wrow+32);
    bf8v b2=*(const bf8v*)(wrow+64);
    bf8v b3=*(const bf8v*)(wrow+96);
    acc[nt]=__builtin_amdgcn_mfma_f32_16x16x32_bf16(af0,b0,acc[nt],0,0,0);
    acc[nt]=__builtin_amdgcn_mfma_f32_16x16x32_bf16(af1,b1,acc[nt],0,0,0);
    acc[nt]=__builtin_amdgcn_mfma_f32_16x16x32_bf16(af2,b2,acc[nt],0,0,0);
    acc[nt]=__builtin_amdgcn_mfma_f32_16x16x32_bf16(af3,b3,acc[nt],0,0,0);
  }
  float v[4][4];
  #pragma unroll
  for(int nt=0;nt<4;nt++)
    #pragma unroll
    for(int r=0;r<4;r++)
      v[nt][r]=fmaxf(acc[nt][r]+bias_nt[nt],0.f);
  if(do_ln){
    #pragma unroll
    for(int r=0;r<4;r++){
      float rs=v[0][r]+v[1][r]+v[2][r]+v[3][r];
      float rss=v[0][r]*v[0][r]+v[1][r]*v[1][r]+v[2][r]*v[2][r]+v[3][r]*v[3][r];
      #pragma unroll
      for(int o=1;o<16;o<<=1){ rs+=__shfl_xor(rs,o,64); rss+=__shfl_xor(rss,o,64); }
      float mu=rs*(1.f/64.f);
      float var=rss*(1.f/64.f)-mu*mu;
      float inv=rsqrtf(var+EPS_);
      #pragma unroll
      for(int nt=0;nt<4;nt++) v[nt][r]=(v[nt][r]-mu)*inv*g_nt[nt]+b_nt[nt];
    }
  }
  size_t rowbase=(size_t)g*N_ + nodebase + w16 + quad*4;
  #pragma unroll
  for(int r=0;r<4;r++){
    unsigned short* out=hd + (rowbase+r)*64;
    #pragma unroll
    for(int nt=0;nt<4;nt++) out[nt*16+m]=f2bf(v[nt][r]);
  }
}

// ---------------- merged readouts; also emit double-bf16 pf rows for md GEMM ----------------
__global__ __launch_bounds__(256) void k_readout2(const unsigned short* __restrict__ h,
    const int* __restrict__ prodi, const int* __restrict__ linei,
    const float* __restrict__ pw, const float* __restrict__ pb,
    const float* __restrict__ fw, const float* __restrict__ fb,
    float* __restrict__ outp, float* __restrict__ outf,
    unsigned short* __restrict__ pfhi, unsigned short* __restrict__ pflo){
  int i=blockIdx.x*256+threadIdx.x;
  const int MP=B_*G_;
  const int MT=MP+B_*F_;
  if(i>=MT) return;
  bool isp=i<MP;
  int j=isp? i : i-MP;
  long n=isp? (long)prodi[j] : (long)linei[j];
  const float* wv=isp? pw:fw;
  float acc=isp? pb[0]:fb[0];
  const uint4* hp=(const uint4*)(h+n*64);
  #pragma unroll
  for(int c=0;c<8;c++){
    uint4 u=hp[c];
    unsigned int uu[4]={u.x,u.y,u.z,u.w};
    #pragma unroll
    for(int q=0;q<4;q++){
      float lo=__uint_as_float(uu[q]<<16);
      float hi=__uint_as_float(uu[q]&0xffff0000u);
      acc += lo*wv[c*8+2*q] + hi*wv[c*8+2*q+1];
    }
  }
  int b,kcol;
  if(isp){ outp[j]=acc; b=j/G_; kcol=j%G_; }
  else   { outf[j]=acc; b=j/F_; kcol=G_+j%F_; }
  unsigned short hi=f2bf(acc);
  pfhi[(long)b*KTOT_+kcol]=hi;
  pflo[(long)b*KTOT_+kcol]=f2bf(acc-bf2f(hi));
}

// ---------------- md dense GEMM: mdT[l][b] += sum_k mask[l][k]*pf[b][k] ----------------
__global__ __launch_bounds__(256) void k_md_gemm(const float* __restrict__ gm, const float* __restrict__ lm,
    const unsigned short* __restrict__ pfhi, const unsigned short* __restrict__ pflo,
    float* __restrict__ mdT){
  int tid=threadIdx.x;
  int w=tid>>6, lane=tid&63;
  int m=lane&15, quad=lane>>4;
  int lb=blockIdx.x>>2, kc=blockIdx.x&3;
  int l=lb*64 + w*16 + m;              // A (mask) row for this lane
  f4v acc[4];
  #pragma unroll
  for(int nt=0;nt<4;nt++) acc[nt]=(f4v){0.f,0.f,0.f,0.f};
  int kk0=kc*KCH_;
  for(int s=0;s<KCH_/32;s++){
    int kk=kk0+s*32;
    const float* ap = (kk<G_)? gm + (long)l*G_ + kk : lm + (long)l*F_ + (kk-G_);
    float4 a0=*(const float4*)(ap+quad*8);
    float4 a1=*(const float4*)(ap+quad*8+4);
    bf8v af;
    af[0]=(short)f2bf(a0.x); af[1]=(short)f2bf(a0.y);
    af[2]=(short)f2bf(a0.z); af[3]=(short)f2bf(a0.w);
    af[4]=(short)f2bf(a1.x); af[5]=(short)f2bf(a1.y);
    af[6]=(short)f2bf(a1.z); af[7]=(short)f2bf(a1.w);
    #pragma unroll
    for(int nt=0;nt<4;nt++){
      int b=nt*16+m;
      const unsigned short* bp=pfhi + (long)b*KTOT_ + kk + quad*8;
      const unsigned short* lp=pflo + (long)b*KTOT_ + kk + quad*8;
      bf8v bh=*(const bf8v*)bp;
      bf8v bl=*(const bf8v*)lp;
      acc[nt]=__builtin_amdgcn_mfma_f32_16x16x32_bf16(af,bh,acc[nt],0,0,0);
      acc[nt]=__builtin_amdgcn_mfma_f32_16x16x32_bf16(af,bl,acc[nt],0,0,0);
    }
  }
  int lrow=lb*64 + w*16 + quad*4;
  #pragma unroll
  for(int r=0;r<4;r++)
    #pragma unroll
    for(int nt=0;nt<4;nt++)
      atomicAdd(&mdT[(long)(lrow+r)*64 + nt*16 + m], acc[nt][r]);
}

__global__ void k_md_final(const float* __restrict__ x, const int* __restrict__ loc,
    const float* __restrict__ mdT, float* __restrict__ md){
  int i=blockIdx.x*256+threadIdx.x;   // i = b*L + l
  if(i<B_*L_){
    int b=i/L_, l=i%L_;
    md[i]=x[(long)loc[i]*7]-mdT[(long)l*64+b];
  }
}

extern "C" void kernel_launch(void* const* d_in, const int* in_sizes, int n_in,
                              void* d_out, int out_size, void* d_ws, size_t ws_size,
                              hipStream_t stream){
  const float* x    =(const float*)d_in[0];
  const int*   ei   =(const int*)d_in[1];
  const int*   prodi=(const int*)d_in[2];
  const int*   linei=(const int*)d_in[3];
  const int*   loci =(const int*)d_in[4];
  const float* ew   =(const float*)d_in[5];
  const float* eb   =(const float*)d_in[6];
  const float* lng  =(const float*)d_in[7];
  const float* lnb  =(const float*)d_in[8];
  const float* wrel =(const float*)d_in[9];
  const float* brel =(const float*)d_in[10];
  const float* wroot=(const float*)d_in[11];
  const float* pw   =(const float*)d_in[12];
  const float* pb   =(const float*)d_in[13];
  const float* fw   =(const float*)d_in[14];
  const float* fb   =(const float*)d_in[15];
  const float* gm   =(const float*)d_in[16];
  const float* lm   =(const float*)d_in[17];

  char* ws=(char*)d_ws;
  unsigned short* hnA =(unsigned short*)ws;                        // NT*64 bf16
  unsigned short* hnB =hnA + (size_t)NT_*64;                       // NT*64 bf16
  unsigned short* wcat=hnB + (size_t)NT_*64;                       // 32768 bf16
  unsigned short* pfhi=wcat + 32768;                               // B*KTOT bf16
  unsigned short* pflo=pfhi + (size_t)B_*KTOT_;                    // B*KTOT bf16
  float* mdT=(float*)(pflo + (size_t)B_*KTOT_);                    // L*64 f32
  int* offT =(int*)(mdT + (size_t)L_*64);                          // 88*65 int
  int* srcs2=offT + 88*65;                                         // 88*TCAP int

  float* outp =(float*)d_out;
  float* outf =outp + (size_t)B_*G_;
  float* outmd=outf + (size_t)B_*F_;

  k_prep<<<600,256,0,stream>>>(ei,mdT,wcat,wrel,wroot,offT,srcs2);
  k_enc<<<NT_/32,256,0,stream>>>(x,hnA,ew,eb,lng,lnb);
  for(int i=0;i<4;i++){
    const unsigned short* hs=(i&1)?hnB:hnA;
    unsigned short* hd=(i&1)?hnA:hnB;
    k_layer<<<B_*(N_/64),256,0,stream>>>(hs,hd,offT,srcs2,wcat+(size_t)i*8192,
        brel+(size_t)i*64,lng,lnb,(i<3)?1:0);
  }
  // after 4 layers (A->B->A->B->A) result is in hnA
  {
    int MT=B_*(G_+F_);
    k_readout2<<<(MT+255)/256,256,0,stream>>>(hnA,prodi,linei,pw,pb,fw,fb,outp,outf,pfhi,pflo);
  }
  k_md_gemm<<<128,256,0,stream>>>(gm,lm,pfhi,pflo,mdT);
  k_md_final<<<(B_*L_)/256,256,0,stream>>>(x,loci,mdT,outmd);
}

// Round 13
// 488.314 us; speedup vs baseline: 1.6765x; 1.0704x over previous
//
#include <hip/hip_runtime.h>

#define B_ 64
#define L_ 2048
#define G_ 512
#define F_ 3072
#define N_ 5632
#define NT_ 360448
#define EG_ 16384
#define E_ 1048576
#define EPS_ 1e-5f
#define CST_ 66      // cat tile stride in ushorts (33 dwords, odd -> ~2-way banks)
#define KTOT_ 3584   // md GEMM K = G + F
#define KCH_ 896     // md GEMM K-chunk (4 chunks)
#define TCAP_ 384    // per-tile edge capacity (realized max span ~255)

typedef __attribute__((ext_vector_type(8))) short bf8v;
typedef __attribute__((ext_vector_type(4))) float f4v;

__device__ __forceinline__ unsigned short f2bf(float f){
  unsigned int u=__float_as_uint(f);
  unsigned int r=(u + 0x7fffu + ((u>>16)&1u))>>16;
  return (unsigned short)r;
}
__device__ __forceinline__ float bf2f(unsigned short h){
  return __uint_as_float(((unsigned int)h)<<16);
}

// ---------------- single prep dispatch ----------------
// blocks 0..87      : per-tile CSR build (LDS hist -> scan -> scatter), packed (src|dst<<16)
// blocks 88..599    : wcat build + outmd demand init
// blocks 600..11863 : encoder + fused LN (produces hnA)
__global__ __launch_bounds__(256) void k_prep(const int* __restrict__ ei,
    unsigned short* __restrict__ wcat,
    const float* __restrict__ wrel, const float* __restrict__ wroot,
    int* __restrict__ offT, int* __restrict__ srcs2,
    const float* __restrict__ x, const int* __restrict__ loci, float* __restrict__ outmd,
    unsigned short* __restrict__ hn, const float* __restrict__ ew, const float* __restrict__ eb,
    const float* __restrict__ lng, const float* __restrict__ lnb){
  int bid=blockIdx.x, tid=threadIdx.x;
  if(bid>=600){
    // ---- encoder + LN ----
    int lane=tid&63, wid=tid>>6;
    int node0=(bid-600)*32+wid*8;
    float w[7];
    #pragma unroll
    for(int k=0;k<7;k++) w[k]=ew[lane*7+k];
    float bias=eb[lane], gam=lng[lane], bet=lnb[lane];
    for(int t=0;t<8;t++){
      long n=node0+t;
      float acc=bias;
      #pragma unroll
      for(int k=0;k<7;k++) acc += x[n*7+k]*w[k];
      acc=fmaxf(acc,0.f);
      float s1=acc, s2=acc*acc;
      #pragma unroll
      for(int o=32;o>0;o>>=1){ s1+=__shfl_xor(s1,o,64); s2+=__shfl_xor(s2,o,64); }
      float mu=s1*(1.f/64.f);
      float var=s2*(1.f/64.f)-mu*mu;
      float inv=rsqrtf(var+EPS_);
      hn[n*64+lane]=f2bf((acc-mu)*inv*gam+bet);
    }
    return;
  }
  if(bid>=88){
    int i=(bid-88)*256+tid;          // 512 blocks -> 131072 = B_*L_
    if(i<B_*L_) outmd[i]=x[(long)loci[i]*7];
    if(i<32768){
      int l=i>>13; int rest=i&8191; int n=rest>>7; int k=rest&127;
      float v=(k<64)? wrel[((long)l*64+n)*64+k] : wroot[((long)l*64+n)*64+(k-64)];
      wcat[i]=f2bf(v);
    }
    return;
  }
  __shared__ int cnt64[64], cur64[64];
  int nb=bid*64;
  if(tid<64) cnt64[tid]=0;
  __syncthreads();
  for(int e=tid;e<EG_;e+=256){
    int d=ei[E_+e];
    unsigned t=(unsigned)(d-nb);
    if(t<64u) atomicAdd(&cnt64[t],1);
  }
  __syncthreads();
  if(tid<64){
    int v=cnt64[tid], s=v;
    #pragma unroll
    for(int o=1;o<64;o<<=1){ int u=__shfl_up(s,o,64); if(tid>=o) s+=u; }
    int ex=s-v;
    offT[bid*65+tid]=ex;
    cur64[tid]=ex;
    if(tid==63) offT[bid*65+64]=s;
  }
  __syncthreads();
  for(int e=tid;e<EG_;e+=256){
    int s=ei[e];
    int d=ei[E_+e];
    unsigned t=(unsigned)(d-nb);
    if(t<64u){
      int p=atomicAdd(&cur64[t],1);
      if(p<TCAP_) srcs2[bid*TCAP_+p]=s|(d<<16);
    }
  }
}

// ---------------- fused layer: pipelined gather -> MFMA -> epilogue (barrier-free) ----------------
// wave w owns dst rows [w*16,w*16+16); lane = channel. 8 blocks/CU for latency cover.
__global__ __launch_bounds__(256,8) void k_layer(const unsigned short* __restrict__ hs,
    unsigned short* __restrict__ hd, const int* __restrict__ offT, const int* __restrict__ srcs2,
    const unsigned short* __restrict__ wcat, const float* __restrict__ brel,
    const float* __restrict__ lng, const float* __restrict__ lnb, int do_ln){
  __shared__ unsigned short cat[64*CST_];
  int tid=threadIdx.x;
  int w=tid>>6, lane=tid&63;
  int bid=blockIdx.x;
  const int P=N_/64;                 // 88 tiles per graph
  int r8=bid/(8*P), rem=bid%(8*P);
  int xcd=rem&7, jj=rem>>3, g=r8*8+xcd;   // one graph per XCD's L2
  int nodebase=jj*64;
  const unsigned short* hg = hs + (size_t)g*N_*64;
  int w16=w*16;

  // ---- phase 1: software-pipelined gather with sorted-dst running flush ----
  {
    int kb=__builtin_amdgcn_readfirstlane(offT[jj*65+w16]);
    int ke=__builtin_amdgcn_readfirstlane(offT[jj*65+w16+16]);
    const int* esp=srcs2 + jj*TCAP_;
    float acc=0.f;
    int dcur=w16;
#define FLUSH_(dd) while(dcur<(dd)){ cat[dcur*CST_+lane]=f2bf(acc); acc=0.f; dcur++; }
    int ng=(ke-kb)>>2;
    int u0=0,u1=0,u2=0,u3=0, v0=0,v1=0,v2=0,v3=0;
    unsigned short a0=0,a1=0,a2=0,a3=0;
    if(ng>0){
      u0=esp[kb];u1=esp[kb+1];u2=esp[kb+2];u3=esp[kb+3];
      a0=hg[(size_t)(u0&0xffff)*64+lane];
      a1=hg[(size_t)(u1&0xffff)*64+lane];
      a2=hg[(size_t)(u2&0xffff)*64+lane];
      a3=hg[(size_t)(u3&0xffff)*64+lane];
    }
    if(ng>1){
      v0=esp[kb+4];v1=esp[kb+5];v2=esp[kb+6];v3=esp[kb+7];
    }
    for(int gi=0;gi<ng;gi++){
      unsigned short b0=0,b1=0,b2=0,b3=0;
      if(gi+1<ng){                    // issue rows for next group (words already resident)
        b0=hg[(size_t)(v0&0xffff)*64+lane];
        b1=hg[(size_t)(v1&0xffff)*64+lane];
        b2=hg[(size_t)(v2&0xffff)*64+lane];
        b3=hg[(size_t)(v3&0xffff)*64+lane];
      }
      int w0=0,w1=0,w2=0,w3=0;
      if(gi+2<ng){                    // fetch edge words two groups ahead
        int kn=kb+(gi+2)*4;
        w0=esp[kn];w1=esp[kn+1];w2=esp[kn+2];w3=esp[kn+3];
      }
      // consume current group's rows
      int d0=(u0>>16)-nodebase; FLUSH_(d0); acc+=bf2f(a0);
      int d1=(u1>>16)-nodebase; FLUSH_(d1); acc+=bf2f(a1);
      int d2=(u2>>16)-nodebase; FLUSH_(d2); acc+=bf2f(a2);
      int d3=(u3>>16)-nodebase; FLUSH_(d3); acc+=bf2f(a3);
      u0=v0;u1=v1;u2=v2;u3=v3;
      v0=w0;v1=w1;v2=w2;v3=w3;
      a0=b0;a1=b1;a2=b2;a3=b3;
    }
    for(int k=kb+ng*4;k<ke;k++){      // tail
      int u=__builtin_amdgcn_readfirstlane(esp[k]);
      unsigned short a=hg[(size_t)(u&0xffff)*64+lane];
      int d=(u>>16)-nodebase; FLUSH_(d); acc+=bf2f(a);
    }
    FLUSH_(w16+16);
#undef FLUSH_
  }
  // no barrier: wave w writes and reads only cat rows [w16, w16+16)

  // ---- phase 2: MFMA [agg|root] @ Wcat^T, fused epilogue ----
  int m=lane&15, quad=lane>>4;
  int row=w16+m;
  const unsigned short* arow=&cat[row*CST_];
  bf8v af0=*(const bf8v*)(arow + quad*8);
  bf8v af1=*(const bf8v*)(arow + 32 + quad*8);
  const unsigned short* hrow=hg+(size_t)(nodebase+row)*64;
  bf8v af2=*(const bf8v*)(hrow+quad*8);
  bf8v af3=*(const bf8v*)(hrow+32+quad*8);
  f4v acc[4];
  float bias_nt[4], g_nt[4], b_nt[4];
  #pragma unroll
  for(int nt=0;nt<4;nt++){
    int c=nt*16+m;
    bias_nt[nt]=brel[c];
    g_nt[nt]=lng[c]; b_nt[nt]=lnb[c];
    acc[nt]=(f4v){0.f,0.f,0.f,0.f};
    const unsigned short* wrow=wcat + (long)c*128 + quad*8;
    bf8v b0=*(const bf8v*)(wrow);
    bf8v b1=*(const bf8v*)(wrow+32);
    bf8v b2=*(const bf8v*)(wrow+64);
    bf8v b3=*(const bf8v*)(wrow+96);
    acc[nt]=__builtin_amdgcn_mfma_f32_16x16x32_bf16(af0,b0,acc[nt],0,0,0);
    acc[nt]=__builtin_amdgcn_mfma_f32_16x16x32_bf16(af1,b1,acc[nt],0,0,0);
    acc[nt]=__builtin_amdgcn_mfma_f32_16x16x32_bf16(af2,b2,acc[nt],0,0,0);
    acc[nt]=__builtin_amdgcn_mfma_f32_16x16x32_bf16(af3,b3,acc[nt],0,0,0);
  }
  float v[4][4];
  #pragma unroll
  for(int nt=0;nt<4;nt++)
    #pragma unroll
    for(int r=0;r<4;r++)
      v[nt][r]=fmaxf(acc[nt][r]+bias_nt[nt],0.f);
  if(do_ln){
    #pragma unroll
    for(int r=0;r<4;r++){
      float rs=v[0][r]+v[1][r]+v[2][r]+v[3][r];
      float rss=v[0][r]*v[0][r]+v[1][r]*v[1][r]+v[2][r]*v[2][r]+v[3][r]*v[3][r];
      #pragma unroll
      for(int o=1;o<16;o<<=1){ rs+=__shfl_xor(rs,o,64); rss+=__shfl_xor(rss,o,64); }
      float mu=rs*(1.f/64.f);
      float var=rss*(1.f/64.f)-mu*mu;
      float inv=rsqrtf(var+EPS_);
      #pragma unroll
      for(int nt=0;nt<4;nt++) v[nt][r]=(v[nt][r]-mu)*inv*g_nt[nt]+b_nt[nt];
    }
  }
  size_t rowbase=(size_t)g*N_ + nodebase + w16 + quad*4;
  #pragma unroll
  for(int r=0;r<4;r++){
    unsigned short* out=hd + (rowbase+r)*64;
    #pragma unroll
    for(int nt=0;nt<4;nt++) out[nt*16+m]=f2bf(v[nt][r]);
  }
}

// ---------------- merged readouts; also emit double-bf16 pf rows for md GEMM ----------------
__global__ __launch_bounds__(256) void k_readout2(const unsigned short* __restrict__ h,
    const int* __restrict__ prodi, const int* __restrict__ linei,
    const float* __restrict__ pw, const float* __restrict__ pb,
    const float* __restrict__ fw, const float* __restrict__ fb,
    float* __restrict__ outp, float* __restrict__ outf,
    unsigned short* __restrict__ pfhi, unsigned short* __restrict__ pflo){
  int i=blockIdx.x*256+threadIdx.x;
  const int MP=B_*G_;
  const int MT=MP+B_*F_;
  if(i>=MT) return;
  bool isp=i<MP;
  int j=isp? i : i-MP;
  long n=isp? (long)prodi[j] : (long)linei[j];
  const float* wv=isp? pw:fw;
  float acc=isp? pb[0]:fb[0];
  const uint4* hp=(const uint4*)(h+n*64);
  #pragma unroll
  for(int c=0;c<8;c++){
    uint4 u=hp[c];
    unsigned int uu[4]={u.x,u.y,u.z,u.w};
    #pragma unroll
    for(int q=0;q<4;q++){
      float lo=__uint_as_float(uu[q]<<16);
      float hi=__uint_as_float(uu[q]&0xffff0000u);
      acc += lo*wv[c*8+2*q] + hi*wv[c*8+2*q+1];
    }
  }
  int b,kcol;
  if(isp){ outp[j]=acc; b=j/G_; kcol=j%G_; }
  else   { outf[j]=acc; b=j/F_; kcol=G_+j%F_; }
  unsigned short hi=f2bf(acc);
  pfhi[(long)b*KTOT_+kcol]=hi;
  pflo[(long)b*KTOT_+kcol]=f2bf(acc-bf2f(hi));
}

// ---------------- md dense GEMM: outmd[b][l] -= sum_k mask[l][k]*pf[b][k] ----------------
// outmd pre-initialized with demand by k_prep; atomics accumulate -acc directly.
__global__ __launch_bounds__(256) void k_md_gemm(const float* __restrict__ gm, const float* __restrict__ lm,
    const unsigned short* __restrict__ pfhi, const unsigned short* __restrict__ pflo,
    float* __restrict__ outmd){
  int tid=threadIdx.x;
  int w=tid>>6, lane=tid&63;
  int m=lane&15, quad=lane>>4;
  int lb=blockIdx.x>>2, kc=blockIdx.x&3;
  int l=lb*64 + w*16 + m;              // A (mask) row for this lane
  f4v acc[4];
  #pragma unroll
  for(int nt=0;nt<4;nt++) acc[nt]=(f4v){0.f,0.f,0.f,0.f};
  int kk0=kc*KCH_;
  for(int s=0;s<KCH_/32;s++){
    int kk=kk0+s*32;
    const float* ap = (kk<G_)? gm + (long)l*G_ + kk : lm + (long)l*F_ + (kk-G_);
    float4 a0=*(const float4*)(ap+quad*8);
    float4 a1=*(const float4*)(ap+quad*8+4);
    bf8v af;
    af[0]=(short)f2bf(a0.x); af[1]=(short)f2bf(a0.y);
    af[2]=(short)f2bf(a0.z); af[3]=(short)f2bf(a0.w);
    af[4]=(short)f2bf(a1.x); af[5]=(short)f2bf(a1.y);
    af[6]=(short)f2bf(a1.z); af[7]=(short)f2bf(a1.w);
    #pragma unroll
    for(int nt=0;nt<4;nt++){
      int b=nt*16+m;
      const unsigned short* bp=pfhi + (long)b*KTOT_ + kk + quad*8;
      const unsigned short* lp=pflo + (long)b*KTOT_ + kk + quad*8;
      bf8v bh=*(const bf8v*)bp;
      bf8v bl=*(const bf8v*)lp;
      acc[nt]=__builtin_amdgcn_mfma_f32_16x16x32_bf16(af,bh,acc[nt],0,0,0);
      acc[nt]=__builtin_amdgcn_mfma_f32_16x16x32_bf16(af,bl,acc[nt],0,0,0);
    }
  }
  int lrow=lb*64 + w*16 + quad*4;
  #pragma unroll
  for(int r=0;r<4;r++)
    #pragma unroll
    for(int nt=0;nt<4;nt++)
      atomicAdd(&outmd[(long)(nt*16+m)*L_ + lrow+r], -acc[nt][r]);
}

extern "C" void kernel_launch(void* const* d_in, const int* in_sizes, int n_in,
                              void* d_out, int out_size, void* d_ws, size_t ws_size,
                              hipStream_t stream){
  const float* x    =(const float*)d_in[0];
  const int*   ei   =(const int*)d_in[1];
  const int*   prodi=(const int*)d_in[2];
  const int*   linei=(const int*)d_in[3];
  const int*   loci =(const int*)d_in[4];
  const float* ew   =(const float*)d_in[5];
  const float* eb   =(const float*)d_in[6];
  const float* lng  =(const float*)d_in[7];
  const float* lnb  =(const float*)d_in[8];
  const float* wrel =(const float*)d_in[9];
  const float* brel =(const float*)d_in[10];
  const float* wroot=(const float*)d_in[11];
  const float* pw   =(const float*)d_in[12];
  const float* pb   =(const float*)d_in[13];
  const float* fw   =(const float*)d_in[14];
  const float* fb   =(const float*)d_in[15];
  const float* gm   =(const float*)d_in[16];
  const float* lm   =(const float*)d_in[17];

  char* ws=(char*)d_ws;
  unsigned short* hnA =(unsigned short*)ws;                        // NT*64 bf16
  unsigned short* hnB =hnA + (size_t)NT_*64;                       // NT*64 bf16
  unsigned short* wcat=hnB + (size_t)NT_*64;                       // 32768 bf16
  unsigned short* pfhi=wcat + 32768;                               // B*KTOT bf16
  unsigned short* pflo=pfhi + (size_t)B_*KTOT_;                    // B*KTOT bf16
  int* offT =(int*)(pflo + (size_t)B_*KTOT_);                      // 88*65 int
  int* srcs2=offT + 88*65;                                         // 88*TCAP int

  float* outp =(float*)d_out;
  float* outf =outp + (size_t)B_*G_;
  float* outmd=outf + (size_t)B_*F_;

  k_prep<<<600+NT_/32,256,0,stream>>>(ei,wcat,wrel,wroot,offT,srcs2,
                                      x,loci,outmd,hnA,ew,eb,lng,lnb);
  for(int i=0;i<4;i++){
    const unsigned short* hs=(i&1)?hnB:hnA;
    unsigned short* hd=(i&1)?hnA:hnB;
    k_layer<<<B_*(N_/64),256,0,stream>>>(hs,hd,offT,srcs2,wcat+(size_t)i*8192,
        brel+(size_t)i*64,lng,lnb,(i<3)?1:0);
  }
  // after 4 layers (A->B->A->B->A) result is in hnA
  {
    int MT=B_*(G_+F_);
    k_readout2<<<(MT+255)/256,256,0,stream>>>(hnA,prodi,linei,pw,pb,fw,fb,outp,outf,pfhi,pflo);
  }
  k_md_gemm<<<128,256,0,stream>>>(gm,lm,pfhi,pflo,outmd);
}